// Round 5
// baseline (4904.709 us; speedup 1.0000x reference)
//
#include <hip/hip_runtime.h>

typedef __attribute__((ext_vector_type(8))) short short8;
typedef __attribute__((ext_vector_type(4))) float f32x4;
typedef __attribute__((ext_vector_type(4))) float float4v;
typedef __attribute__((ext_vector_type(4))) unsigned short u16x4;
typedef __attribute__((ext_vector_type(4))) unsigned int u32x4;

#define T_TOT   1024
#define BATCH   64
#define HID     512
#define G4      2048
#define NGRID   128     // 4 batch-tiles x 32 hid-tiles

static __device__ __forceinline__ unsigned short f2bf(float x) {
  union { float f; unsigned u; } v; v.f = x;
  unsigned r = v.u + 0x7FFFu + ((v.u >> 16) & 1u);
  return (unsigned short)(r >> 16);
}
static __device__ __forceinline__ float sigm(float x) {
  return 1.0f / (1.0f + __expf(-x));
}
static __device__ __forceinline__ float tanh_fast(float x) {
  return 1.0f - 2.0f / (__expf(2.0f * x) + 1.0f);
}

// ---------------------------------------------------------------- init
// hb2: 2 x [64][512] u32, word = (tag16 << 16) | bf16(h). parity0 = tag 0 + h0,
// parity1 = tag 0xFFFF (never matches t<=1024) -> deterministic across replays.
__global__ void init_k(const float* __restrict__ h0, const float* __restrict__ c0,
                       unsigned int* __restrict__ hb2, float* __restrict__ cst,
                       float* __restrict__ hst) {
  const int i = blockIdx.x * 256 + threadIdx.x;
  if (i < BATCH * HID) {
    const float h = h0[i];
    hb2[i] = (unsigned)f2bf(h);               // tag 0 | h0
    hb2[BATCH * HID + i] = 0xFFFF0000u;       // invalid tag
    hst[i] = h;
    cst[i] = c0[i];
  }
}

// --------------------------------------------------- xz = x@W_ih^T + b
__global__ __launch_bounds__(256) void xz_gemm(
    const float* __restrict__ A, const float* __restrict__ W,
    const float* __restrict__ bih, const float* __restrict__ bhh,
    float* __restrict__ out) {
  __shared__ unsigned short As[128 * 64];
  __shared__ unsigned short Bs[128 * 64];
  const int tid  = threadIdx.x;
  const int lane = tid & 63;
  const int wid  = tid >> 6;
  const int wm   = (wid >> 1) * 64;
  const int wn   = (wid & 1) * 64;
  const int l15  = lane & 15;
  const int l4   = lane >> 4;
  const long bm  = blockIdx.x;
  const long bn  = blockIdx.y;

  f32x4 acc[4][4];
#pragma unroll
  for (int mt = 0; mt < 4; ++mt)
#pragma unroll
    for (int nt = 0; nt < 4; ++nt) acc[mt][nt] = f32x4{0.f, 0.f, 0.f, 0.f};

  const float* Ab = A + bm * 128 * 512;
  const float* Wb = W + bn * 128 * 512;
  const int r0 = tid >> 4;
  const int cq = (tid & 15) * 4;

  for (int k0 = 0; k0 < 512; k0 += 64) {
#pragma unroll
    for (int pass = 0; pass < 8; ++pass) {
      const int r = pass * 16 + r0;
      const float4v va = *(const float4v*)(Ab + (long)r * 512 + k0 + cq);
      const float4v vb = *(const float4v*)(Wb + (long)r * 512 + k0 + cq);
      u16x4 pa, pb;
#pragma unroll
      for (int j = 0; j < 4; ++j) { pa[j] = f2bf(va[j]); pb[j] = f2bf(vb[j]); }
      const int boff = r * 128 + ((cq * 2) ^ ((r & 7) << 4));
      *(u16x4*)((char*)As + boff) = pa;
      *(u16x4*)((char*)Bs + boff) = pb;
    }
    __syncthreads();
#pragma unroll
    for (int kk = 0; kk < 2; ++kk) {
      short8 af[4], bfv[4];
#pragma unroll
      for (int mt = 0; mt < 4; ++mt) {
        const int row = wm + mt * 16 + l15;
        af[mt] = *(const short8*)((const char*)As + row * 128 +
                                  ((kk * 64 + l4 * 16) ^ ((row & 7) << 4)));
      }
#pragma unroll
      for (int nt = 0; nt < 4; ++nt) {
        const int row = wn + nt * 16 + l15;
        bfv[nt] = *(const short8*)((const char*)Bs + row * 128 +
                                   ((kk * 64 + l4 * 16) ^ ((row & 7) << 4)));
      }
#pragma unroll
      for (int mt = 0; mt < 4; ++mt)
#pragma unroll
        for (int nt = 0; nt < 4; ++nt)
          acc[mt][nt] = __builtin_amdgcn_mfma_f32_16x16x32_bf16(af[mt], bfv[nt], acc[mt][nt], 0, 0, 0);
    }
    __syncthreads();
  }

#pragma unroll
  for (int nt = 0; nt < 4; ++nt) {
    const long gn = bn * 128 + wn + nt * 16 + l15;
    const float bias = bih[gn] + bhh[gn];
#pragma unroll
    for (int mt = 0; mt < 4; ++mt) {
      const long gm0 = bm * 128 + wm + mt * 16 + l4 * 4;
#pragma unroll
      for (int r = 0; r < 4; ++r)
        out[(gm0 + r) * G4 + gn] = acc[mt][nt][r] + bias;
    }
  }
}

// ------------------------------------------------------- recurrent core
// Grid 128 = 4 batch-tiles (mb) x 32 hid-tiles (nb). Block (mb,nb) owns the
// [16 batch x 16 hid] state patch, all 4 gates. Exchange words carry their
// own validity tag -> no fences, no drains, no flags: producers just store,
// consumers poll the data itself (detect == load).
__global__ __launch_bounds__(256, 1) void lstm_steps(
    const float* __restrict__ xz,      // [Tc][64][2048]
    const float* __restrict__ Whh,     // [2048][512]
    const float* __restrict__ alpha_p,
    float* __restrict__ out,           // d_out
    unsigned int* __restrict__ hb2,    // 2 x [64][512] tagged u32
    float* __restrict__ cst, float* __restrict__ hst,
    int t0, int Tc) {
  const int bx  = blockIdx.x;
  const int mb  = bx >> 5;         // batch tile 0..3
  const int nb  = bx & 31;         // hid tile 0..31
  const int rb0 = mb * 16;
  const int hs0 = nb * 16;
  const int tid = threadIdx.x;
  const int lane = tid & 63;
  const int wid = tid >> 6;        // gate index
  const int l15 = lane & 15;
  const int l4  = lane >> 4;

  // h rows in LDS as 16B chunks: addr = c*256 + ((r ^ (c&15))<<4)
  // (r = batch row 0..15, c = K-chunk 0..63). Writes land 8 lanes/bank-quad
  // (exact floor); reads identical to R4's verified pattern.
  __shared__ __align__(16) unsigned short h_lds[16 * HID];   // 16 KB
  __shared__ __align__(16) float gates[4][16][20];
  __shared__ float c_s[16][17];
  __shared__ float h_s[16][17];

  // W_hh fragments: gate wid, hid cols hs0..hs0+15, full K=512 (64 VGPRs).
  short8 wf[16];
  {
    const float* wr = Whh + (long)(wid * HID + hs0 + l15) * HID + l4 * 8;
#pragma unroll
    for (int ks = 0; ks < 16; ++ks) {
      const float4v lo = *(const float4v*)(wr + ks * 32);
      const float4v hi = *(const float4v*)(wr + ks * 32 + 4);
      short8 f;
#pragma unroll
      for (int j = 0; j < 4; ++j) {
        f[j]     = (short)f2bf(lo[j]);
        f[j + 4] = (short)f2bf(hi[j]);
      }
      wf[ks] = f;
    }
  }
  const float a = alpha_p[0];
  const float oma = 1.0f - a;

  const int em = tid >> 4;          // elementwise row 0..15
  const int en = tid & 15;          // elementwise col 0..15
  c_s[em][en] = cst[(long)(rb0 + em) * HID + hs0 + en];
  h_s[em][en] = hst[(long)(rb0 + em) * HID + hs0 + en];
  __syncthreads();

  const long YS = (long)T_TOT * BATCH * HID;
  // Sweep source: this thread owns row rb0+(tid>>4), 32 consecutive cols.
  const int swr = tid >> 4;
  const int swc = (tid & 15) * 32;

  for (int tt = 0; tt < Tc; ++tt) {
    const int t = t0 + tt;

    // xz prefetch (16 scattered f32) — rides under the poll's vmcnt.
    f32x4 acc[4];
    {
      const float* xzt = xz + ((long)tt * BATCH + rb0 + l4 * 4) * G4 +
                         wid * HID + hs0 + l15;
#pragma unroll
      for (int r = 0; r < 4; ++r) acc[0][r] = xzt[(long)r * G4];
    }
    acc[1] = f32x4{0.f, 0.f, 0.f, 0.f};
    acc[2] = acc[1];
    acc[3] = acc[1];

    // ---- tagged poll-sweep: detect == data load ----
    u32x4 sv[8];
    {
      const unsigned int* hsrc = hb2 + (size_t)(t & 1) * (BATCH * HID) +
                                 (long)(rb0 + swr) * HID + swc;
#pragma unroll
      for (int i = 0; i < 8; ++i)
        asm volatile("global_load_dwordx4 %0, %1, off sc0 sc1"
                     : "=v"(sv[i]) : "v"(hsrc + i * 4));
      const unsigned wantHi = ((unsigned)(t & 0xffff)) << 16;
      for (;;) {
        asm volatile("s_waitcnt vmcnt(0)" ::: "memory");
        unsigned diff = 0u;
#pragma unroll
        for (int i = 0; i < 8; ++i)
#pragma unroll
          for (int j = 0; j < 4; ++j)
            diff |= (sv[i][j] ^ wantHi) & 0xFFFF0000u;
        if (diff == 0u) break;
#pragma unroll
        for (int i = 0; i < 8; ++i)
          asm volatile("global_load_dwordx4 %0, %1, off sc0 sc1"
                       : "=v"(sv[i]) : "v"(hsrc + i * 4));
      }
    }

    // Pack lo16 pairs (v_perm) -> 4 x ds_write_b128 at the bank floor.
#pragma unroll
    for (int jj = 0; jj < 4; ++jj) {
      u32x4 pk;
#pragma unroll
      for (int q = 0; q < 2; ++q) {
        pk[2 * q]     = __builtin_amdgcn_perm(sv[jj * 2 + q][1], sv[jj * 2 + q][0], 0x05040100u);
        pk[2 * q + 1] = __builtin_amdgcn_perm(sv[jj * 2 + q][3], sv[jj * 2 + q][2], 0x05040100u);
      }
      const int c = (tid & 15) * 4 + jj;
      *(u32x4*)((char*)h_lds + c * 256 + ((swr ^ (c & 15)) << 4)) = pk;
    }
    __syncthreads();

    // [16 x 16] = h[16 x 512] @ W^T, 4 interleaved accumulator chains.
#pragma unroll
    for (int ks = 0; ks < 16; ++ks) {
      const int c = ks * 4 + l4;
      const short8 af = *(const short8*)((const char*)h_lds + c * 256 +
                                         ((l15 ^ (c & 15)) << 4));
      acc[ks & 3] = __builtin_amdgcn_mfma_f32_16x16x32_bf16(af, wf[ks], acc[ks & 3], 0, 0, 0);
    }
    {
      const f32x4 s01 = acc[0] + acc[1];
      const f32x4 s23 = acc[2] + acc[3];
      const f32x4 s = s01 + s23;
#pragma unroll
      for (int r = 0; r < 4; ++r)
        gates[wid][l4 * 4 + r][l15] = s[r];
    }
    __syncthreads();

    // Elementwise: one element per thread.
    const float gi = gates[0][em][en], gf = gates[1][em][en];
    const float gg = gates[2][em][en], go = gates[3][em][en];
    const float ii = sigm(gi), ff = sigm(gf), oo = sigm(go);
    const float g  = tanh_fast(gg);
    const float cp = c_s[em][en], hp = h_s[em][en];
    const float cn = ff * cp + ii * g;
    const float hn = oo * tanh_fast(cn);
    const float co = a * cn + oma * cp;
    const float ho = a * hn + oma * hp;
    c_s[em][en] = co;
    h_s[em][en] = ho;

    // Self-validating exchange store: tag(t+1) | bf16(h'). No drain, no flag.
    {
      unsigned int* dst = hb2 + (size_t)((t + 1) & 1) * (BATCH * HID) +
                          (long)(rb0 + em) * HID + hs0 + en;
      const unsigned w32 = (((unsigned)((t + 1) & 0xffff)) << 16) |
                           (unsigned)f2bf(ho);
      asm volatile("global_store_dword %0, %1, off sc0 sc1"
                   :: "v"((const void*)dst), "v"(w32) : "memory");
    }

    // Off-critical-path output stores.
    out[((long)t * BATCH + rb0 + em) * HID + hs0 + en] = ho;
    if (t == T_TOT - 1) {
      out[YS + (long)(rb0 + em) * HID + hs0 + en] = ho;
      out[YS + BATCH * HID + (long)(rb0 + em) * HID + hs0 + en] = co;
    }
  }

  // Persist state for the next chunk.
  cst[(long)(rb0 + em) * HID + hs0 + en] = c_s[em][en];
  hst[(long)(rb0 + em) * HID + hs0 + en] = h_s[em][en];
}

// ---------------------------------------------------------------- host
extern "C" void kernel_launch(void* const* d_in, const int* in_sizes, int n_in,
                              void* d_out, int out_size, void* d_ws, size_t ws_size,
                              hipStream_t stream) {
  const float* x     = (const float*)d_in[0];
  const float* h0    = (const float*)d_in[1];
  const float* c0    = (const float*)d_in[2];
  const float* W_ih  = (const float*)d_in[3];
  const float* W_hh  = (const float*)d_in[4];
  const float* b_ih  = (const float*)d_in[5];
  const float* b_hh  = (const float*)d_in[6];
  const float* alpha = (const float*)d_in[7];
  float* out = (float*)d_out;

  char* ws = (char*)d_ws;
  unsigned int* hb2 = (unsigned int*)(ws + 0);              // 256 KB tagged h
  float* cst = (float*)(ws + 262144);                       // 128 KB
  float* hst = (float*)(ws + 393216);                       // 128 KB
  float* xzb = (float*)(ws + 524288);                       // Tc*512 KB

  int Tc = T_TOT;
  while ((size_t)Tc * 524288ull + 524288ull > ws_size && Tc > 2) Tc >>= 1;

  init_k<<<128, 256, 0, stream>>>(h0, c0, hb2, cst, hst);
  for (int t0 = 0; t0 < T_TOT; t0 += Tc) {
    dim3 gg(Tc / 2, 16);
    xz_gemm<<<gg, 256, 0, stream>>>(x + (size_t)t0 * BATCH * 512,
                                    W_ih, b_ih, b_hh, xzb);
    lstm_steps<<<NGRID, 256, 0, stream>>>(xzb, W_hh, alpha, out, hb2,
                                          cst, hst, t0, Tc);
  }
}

// Round 6
// 3021.291 us; speedup vs baseline: 1.6234x; 1.6234x over previous
//
#include <hip/hip_runtime.h>

typedef __attribute__((ext_vector_type(8))) short short8;
typedef __attribute__((ext_vector_type(4))) float f32x4;
typedef __attribute__((ext_vector_type(4))) float float4v;
typedef __attribute__((ext_vector_type(4))) unsigned short u16x4;
typedef __attribute__((ext_vector_type(4))) unsigned int u32x4;

#define T_TOT   1024
#define BATCH   64
#define HID     512
#define G4      2048
#define NGRID   128     // 4 batch-tiles x 32 hid-tiles
#define BH      (BATCH * HID)

static __device__ __forceinline__ unsigned short f2bf(float x) {
  union { float f; unsigned u; } v; v.f = x;
  unsigned r = v.u + 0x7FFFu + ((v.u >> 16) & 1u);
  return (unsigned short)(r >> 16);
}
static __device__ __forceinline__ float sigm(float x) {
  return 1.0f / (1.0f + __expf(-x));
}
static __device__ __forceinline__ float tanh_fast(float x) {
  return 1.0f - 2.0f / (__expf(2.0f * x) + 1.0f);
}
// LDS-only barrier: does NOT drain vmcnt (unlike __syncthreads, which the
// compiler lowers with a full s_waitcnt vmcnt(0) — that would put in-flight
// global stores on the critical path every step).
static __device__ __forceinline__ void bar_lds() {
  asm volatile("s_waitcnt lgkmcnt(0)" ::: "memory");
  __builtin_amdgcn_s_barrier();
  asm volatile("" ::: "memory");
}

// ---------------------------------------------------------------- init
// hb2: 2 x [64][512] u32, word = (tag16 << 16) | bf16(h). parity0 = tag 0 + h0,
// parity1 = invalid tag -> deterministic across graph replays.
__global__ void init_k(const float* __restrict__ h0, const float* __restrict__ c0,
                       unsigned int* __restrict__ hb2, float* __restrict__ cst,
                       float* __restrict__ hst, unsigned int* __restrict__ fin) {
  const int i = blockIdx.x * 256 + threadIdx.x;
  if (i < T_TOT * NGRID) fin[i] = 0u;
  if (i < BH) {
    const float h = h0[i];
    hb2[i] = (unsigned)f2bf(h);               // tag 0 | h0
    hb2[BH + i] = 0xFFFF0000u;                // invalid tag
    hst[i] = h;
    cst[i] = c0[i];
  }
}

// --------------------------------------------------- xz = x@W_ih^T + b
// Output repacked block-contiguous for the consumer:
// xzp[((t*4 + mb)*32 + nb)][em 0..15][gate 0..3][en 0..15]  (f32)
__global__ __launch_bounds__(256) void xz_gemm(
    const float* __restrict__ A, const float* __restrict__ W,
    const float* __restrict__ bih, const float* __restrict__ bhh,
    float* __restrict__ xzp) {
  __shared__ unsigned short As[128 * 64];
  __shared__ unsigned short Bs[128 * 64];
  const int tid  = threadIdx.x;
  const int lane = tid & 63;
  const int wid  = tid >> 6;
  const int wm   = (wid >> 1) * 64;
  const int wn   = (wid & 1) * 64;
  const int l15  = lane & 15;
  const int l4   = lane >> 4;
  const long bm  = blockIdx.x;
  const long bn  = blockIdx.y;

  f32x4 acc[4][4];
#pragma unroll
  for (int mt = 0; mt < 4; ++mt)
#pragma unroll
    for (int nt = 0; nt < 4; ++nt) acc[mt][nt] = f32x4{0.f, 0.f, 0.f, 0.f};

  const float* Ab = A + bm * 128 * 512;
  const float* Wb = W + bn * 128 * 512;
  const int r0 = tid >> 4;
  const int cq = (tid & 15) * 4;

  for (int k0 = 0; k0 < 512; k0 += 64) {
#pragma unroll
    for (int pass = 0; pass < 8; ++pass) {
      const int r = pass * 16 + r0;
      const float4v va = *(const float4v*)(Ab + (long)r * 512 + k0 + cq);
      const float4v vb = *(const float4v*)(Wb + (long)r * 512 + k0 + cq);
      u16x4 pa, pb;
#pragma unroll
      for (int j = 0; j < 4; ++j) { pa[j] = f2bf(va[j]); pb[j] = f2bf(vb[j]); }
      const int boff = r * 128 + ((cq * 2) ^ ((r & 7) << 4));
      *(u16x4*)((char*)As + boff) = pa;
      *(u16x4*)((char*)Bs + boff) = pb;
    }
    __syncthreads();
#pragma unroll
    for (int kk = 0; kk < 2; ++kk) {
      short8 af[4], bfv[4];
#pragma unroll
      for (int mt = 0; mt < 4; ++mt) {
        const int row = wm + mt * 16 + l15;
        af[mt] = *(const short8*)((const char*)As + row * 128 +
                                  ((kk * 64 + l4 * 16) ^ ((row & 7) << 4)));
      }
#pragma unroll
      for (int nt = 0; nt < 4; ++nt) {
        const int row = wn + nt * 16 + l15;
        bfv[nt] = *(const short8*)((const char*)Bs + row * 128 +
                                   ((kk * 64 + l4 * 16) ^ ((row & 7) << 4)));
      }
#pragma unroll
      for (int mt = 0; mt < 4; ++mt)
#pragma unroll
        for (int nt = 0; nt < 4; ++nt)
          acc[mt][nt] = __builtin_amdgcn_mfma_f32_16x16x32_bf16(af[mt], bfv[nt], acc[mt][nt], 0, 0, 0);
    }
    __syncthreads();
  }

#pragma unroll
  for (int nt = 0; nt < 4; ++nt) {
    const int gn = (int)(bn * 128) + wn + nt * 16 + l15;
    const float bias = bih[gn] + bhh[gn];
    const int g2  = gn >> 9;          // gate
    const int hh  = gn & 511;
    const int nb2 = hh >> 4;
    const int en2 = hh & 15;
#pragma unroll
    for (int mt = 0; mt < 4; ++mt) {
      const int m0 = (int)(bm * 128) + wm + mt * 16 + l4 * 4;
#pragma unroll
      for (int r = 0; r < 4; ++r) {
        const int m = m0 + r;
        const int tt2 = m >> 6, brow = m & 63;
        const int mb2 = brow >> 4, em2 = brow & 15;
        xzp[((((size_t)tt2 * 4 + mb2) * 32 + nb2) << 10) + em2 * 64 + g2 * 16 + en2] =
            acc[mt][nt][r] + bias;
      }
    }
  }
}

// ------------------------------------------------------- recurrent core
// Grid 128 = 4 batch-tiles (mb) x 32 hid-tiles (nb). Block (mb,nb) owns the
// [16 x 16] state patch, all 4 gates. Exchange words are self-validating
// (tag | bf16): producers never drain; the flag is only an advisory gate so
// consumers rarely retry. Consumers tag-validate per 32B granule.
__global__ __launch_bounds__(256, 1) void lstm_steps(
    const float* __restrict__ xzp,     // [Tc*4*32][1024]
    const float* __restrict__ Whh,     // [2048][512]
    const float* __restrict__ alpha_p,
    float* __restrict__ out,           // d_out
    unsigned int* __restrict__ hb2,    // 2 x [64][512] tagged u32
    float* __restrict__ cst, float* __restrict__ hst,
    unsigned int* fin,                 // [T_TOT][4][32]
    int t0, int Tc) {
  const int bx  = blockIdx.x;
  const int mb  = bx >> 5;
  const int nb  = bx & 31;
  const int rb0 = mb * 16;
  const int hs0 = nb * 16;
  const int tid = threadIdx.x;
  const int lane = tid & 63;
  const int w   = tid >> 6;        // wave = gate index
  const int l15 = lane & 15;
  const int l4  = lane >> 4;

  // h rows as 16B chunks: addr = c*256 + ((r ^ (c&15))<<4)   (R4-proven floor)
  __shared__ __align__(16) unsigned short h_lds[16 * HID];   // 16 KB
  __shared__ __align__(16) float gates[4][16][20];

  // W_hh fragments: gate w, hid cols hs0..hs0+15, full K=512 (64 VGPRs).
  short8 wf[16];
  {
    const float* wr = Whh + (long)(w * HID + hs0 + l15) * HID + l4 * 8;
#pragma unroll
    for (int ks = 0; ks < 16; ++ks) {
      const float4v lo = *(const float4v*)(wr + ks * 32);
      const float4v hi = *(const float4v*)(wr + ks * 32 + 4);
      short8 f;
#pragma unroll
      for (int j = 0; j < 4; ++j) {
        f[j]     = (short)f2bf(lo[j]);
        f[j + 4] = (short)f2bf(hi[j]);
      }
      wf[ks] = f;
    }
  }
  const float a = alpha_p[0];
  const float oma = 1.0f - a;

  const int em = tid >> 4;          // elementwise row 0..15
  const int en = tid & 15;          // elementwise col 0..15
  float cp = cst[(long)(rb0 + em) * HID + hs0 + en];
  float hp = hst[(long)(rb0 + em) * HID + hs0 + en];

  const long YS = (long)T_TOT * BATCH * HID;

  for (int tt = 0; tt < Tc; ++tt) {
    const int t = t0 + tt;

    // xz prefetch (4 coalesced f32 from the 4KB block-contiguous slice).
    f32x4 acc[4];
    {
      const float* xb = xzp + ((((size_t)tt * 4 + mb) * 32 + nb) << 10) +
                        w * 16 + l15;
#pragma unroll
      for (int r = 0; r < 4; ++r) acc[0][r] = xb[(l4 * 4 + r) * 64];
    }
    acc[1] = f32x4{0.f, 0.f, 0.f, 0.f};
    acc[2] = acc[1];
    acc[3] = acc[1];

    // Advisory flag gate (1 dword/lane, one 128B line). Tags do the real
    // validation below, so no producer-side drain is needed anywhere.
    if (t > 0) {
      const unsigned int* fl = fin + ((size_t)(t - 1) * 4 + mb) * 32;
      while (true) {
        const unsigned v = __hip_atomic_load(&fl[lane & 31], __ATOMIC_RELAXED,
                                             __HIP_MEMORY_SCOPE_AGENT);
        if (__all(v != 0)) break;
      }
      asm volatile("" ::: "memory");
    }

    // Tagged data load: 8 x dwordx4 (rows 4i+w, cols lane*8..+8), validate
    // per 32B granule, selectively reload failures (normally zero).
    u32x4 sa[4], sb[4];
    {
      const unsigned int* p0 = hb2 + (size_t)(t & 1) * BH +
                               (size_t)(rb0 + w) * HID + lane * 8;
#pragma unroll
      for (int i = 0; i < 4; ++i) {
        const unsigned int* p = p0 + (size_t)i * 4 * HID;
        asm volatile("global_load_dwordx4 %0, %1, off sc0 sc1" : "=v"(sa[i]) : "v"(p));
        asm volatile("global_load_dwordx4 %0, %1, off sc0 sc1" : "=v"(sb[i]) : "v"(p + 4));
      }
      const unsigned wantHi = ((unsigned)t) << 16;
      for (;;) {
        asm volatile("s_waitcnt vmcnt(0)" ::: "memory");
        __builtin_amdgcn_sched_barrier(0);
        unsigned bad = 0u;
#pragma unroll
        for (int i = 0; i < 4; ++i) {
          unsigned d = 0u;
#pragma unroll
          for (int j = 0; j < 4; ++j)
            d |= ((sa[i][j] ^ wantHi) | (sb[i][j] ^ wantHi));
          if (d & 0xFFFF0000u) bad |= (1u << i);
        }
        if (!__any(bad)) break;
#pragma unroll
        for (int i = 0; i < 4; ++i)
          if (bad & (1u << i)) {
            const unsigned int* p = p0 + (size_t)i * 4 * HID;
            asm volatile("global_load_dwordx4 %0, %1, off sc0 sc1" : "=v"(sa[i]) : "v"(p));
            asm volatile("global_load_dwordx4 %0, %1, off sc0 sc1" : "=v"(sb[i]) : "v"(p + 4));
          }
      }
    }

    // Pack lo16s -> one 16B chunk per (row, c=lane); R4-proven write pattern.
#pragma unroll
    for (int i = 0; i < 4; ++i) {
      u32x4 pk;
      pk[0] = __builtin_amdgcn_perm(sa[i][1], sa[i][0], 0x05040100u);
      pk[1] = __builtin_amdgcn_perm(sa[i][3], sa[i][2], 0x05040100u);
      pk[2] = __builtin_amdgcn_perm(sb[i][1], sb[i][0], 0x05040100u);
      pk[3] = __builtin_amdgcn_perm(sb[i][3], sb[i][2], 0x05040100u);
      const int r = 4 * i + w;
      const int c = lane;
      *(u32x4*)((char*)h_lds + c * 256 + ((r ^ (c & 15)) << 4)) = pk;
    }
    bar_lds();

    // [16 x 16] = h[16 x 512] @ W^T, 4 interleaved accumulator chains.
#pragma unroll
    for (int ks = 0; ks < 16; ++ks) {
      const int c = ks * 4 + l4;
      const short8 af = *(const short8*)((const char*)h_lds + c * 256 +
                                         ((l15 ^ (c & 15)) << 4));
      acc[ks & 3] = __builtin_amdgcn_mfma_f32_16x16x32_bf16(af, wf[ks], acc[ks & 3], 0, 0, 0);
    }
    {
      const f32x4 s = (acc[0] + acc[1]) + (acc[2] + acc[3]);
#pragma unroll
      for (int r = 0; r < 4; ++r)
        gates[w][l4 * 4 + r][l15] = s[r];
    }
    bar_lds();

    // Elementwise: one element per thread; c/h state lives in registers.
    const float gi = gates[0][em][en], gf = gates[1][em][en];
    const float gg = gates[2][em][en], go = gates[3][em][en];
    const float ii = sigm(gi), ff = sigm(gf), oo = sigm(go);
    const float g  = tanh_fast(gg);
    const float cn = ff * cp + ii * g;
    const float hn = oo * tanh_fast(cn);
    const float co = a * cn + oma * cp;
    const float ho = a * hn + oma * hp;
    cp = co;
    hp = ho;

    // Self-validating exchange store: tag(t+1) | bf16(h'). No drain.
    {
      unsigned int* dst = hb2 + (size_t)((t + 1) & 1) * BH +
                          (long)(rb0 + em) * HID + hs0 + en;
      const unsigned w32 = (((unsigned)(t + 1)) << 16) | (unsigned)f2bf(ho);
      asm volatile("global_store_dword %0, %1, off sc0 sc1"
                   :: "v"((const void*)dst), "v"(w32) : "memory");
    }
    // Raw barrier (no vmcnt drain): all threads have ISSUED their stores;
    // then publish the advisory flag.
    __builtin_amdgcn_s_barrier();
    asm volatile("" ::: "memory");
    if (tid == 0)
      __hip_atomic_store(&fin[((size_t)t * 4 + mb) * 32 + nb], 1u,
                         __ATOMIC_RELAXED, __HIP_MEMORY_SCOPE_AGENT);

    // Off-critical-path output stores.
    out[((long)t * BATCH + rb0 + em) * HID + hs0 + en] = ho;
    if (t == T_TOT - 1) {
      out[YS + (long)(rb0 + em) * HID + hs0 + en] = ho;
      out[YS + BATCH * HID + (long)(rb0 + em) * HID + hs0 + en] = co;
    }
  }

  // Persist state for the next chunk.
  cst[(long)(rb0 + em) * HID + hs0 + en] = cp;
  hst[(long)(rb0 + em) * HID + hs0 + en] = hp;
}

// ---------------------------------------------------------------- host
extern "C" void kernel_launch(void* const* d_in, const int* in_sizes, int n_in,
                              void* d_out, int out_size, void* d_ws, size_t ws_size,
                              hipStream_t stream) {
  const float* x     = (const float*)d_in[0];
  const float* h0    = (const float*)d_in[1];
  const float* c0    = (const float*)d_in[2];
  const float* W_ih  = (const float*)d_in[3];
  const float* W_hh  = (const float*)d_in[4];
  const float* b_ih  = (const float*)d_in[5];
  const float* b_hh  = (const float*)d_in[6];
  const float* alpha = (const float*)d_in[7];
  float* out = (float*)d_out;

  char* ws = (char*)d_ws;
  unsigned int* fin = (unsigned int*)(ws + 0);              // 512 KB [T][4][32]
  unsigned int* hb2 = (unsigned int*)(ws + 524288);         // 256 KB tagged h
  float* cst = (float*)(ws + 786432);                       // 128 KB
  float* hst = (float*)(ws + 917504);                       // 128 KB
  float* xzp = (float*)(ws + 1048576);                      // Tc*512 KB

  int Tc = T_TOT;
  while ((size_t)Tc * 524288ull + 1048576ull > ws_size && Tc > 2) Tc >>= 1;

  init_k<<<512, 256, 0, stream>>>(h0, c0, hb2, cst, hst, fin);
  for (int t0 = 0; t0 < T_TOT; t0 += Tc) {
    dim3 gg(Tc / 2, 16);
    xz_gemm<<<gg, 256, 0, stream>>>(x + (size_t)t0 * BATCH * 512,
                                    W_ih, b_ih, b_hh, xzp);
    lstm_steps<<<NGRID, 256, 0, stream>>>(xzp, W_hh, alpha, out, hb2,
                                          cst, hst, fin, t0, Tc);
  }
}

// Round 7
// 2946.564 us; speedup vs baseline: 1.6646x; 1.0254x over previous
//
#include <hip/hip_runtime.h>

typedef __attribute__((ext_vector_type(8))) short short8;
typedef __attribute__((ext_vector_type(4))) float f32x4;
typedef __attribute__((ext_vector_type(4))) float float4v;
typedef __attribute__((ext_vector_type(4))) unsigned short u16x4;
typedef __attribute__((ext_vector_type(4))) unsigned int u32x4;

#define T_TOT   1024
#define BATCH   64
#define HID     512
#define G4      2048
#define NGRID   128     // 4 batch-tiles x 32 hid-tiles
#define BH      (BATCH * HID)

static __device__ __forceinline__ unsigned short f2bf(float x) {
  union { float f; unsigned u; } v; v.f = x;
  unsigned r = v.u + 0x7FFFu + ((v.u >> 16) & 1u);
  return (unsigned short)(r >> 16);
}
static __device__ __forceinline__ float sigm(float x) {
  return 1.0f / (1.0f + __expf(-x));
}
static __device__ __forceinline__ float tanh_fast(float x) {
  return 1.0f - 2.0f / (__expf(2.0f * x) + 1.0f);
}
// LDS-only barrier: does NOT drain vmcnt (unlike __syncthreads).
static __device__ __forceinline__ void bar_lds() {
  asm volatile("s_waitcnt lgkmcnt(0)" ::: "memory");
  __builtin_amdgcn_s_barrier();
  asm volatile("" ::: "memory");
}

// ---------------------------------------------------------------- init
// hb2: 2 x [64][512] u32, word = (tag16 << 16) | bf16(h). parity0 = tag 0 + h0,
// parity1 = invalid tag -> deterministic across graph replays.
__global__ void init_k(const float* __restrict__ h0, const float* __restrict__ c0,
                       unsigned int* __restrict__ hb2, float* __restrict__ cst,
                       float* __restrict__ hst) {
  const int i = blockIdx.x * 256 + threadIdx.x;
  if (i < BH) {
    const float h = h0[i];
    hb2[i] = (unsigned)f2bf(h);               // tag 0 | h0
    hb2[BH + i] = 0xFFFF0000u;                // invalid tag
    hst[i] = h;
    cst[i] = c0[i];
  }
}

// --------------------------------------------------- xz = x@W_ih^T + b
// Output repacked block-contiguous for the consumer:
// xzp[((t*4 + mb)*32 + nb)][em 0..15][gate 0..3][en 0..15]  (f32)
__global__ __launch_bounds__(256) void xz_gemm(
    const float* __restrict__ A, const float* __restrict__ W,
    const float* __restrict__ bih, const float* __restrict__ bhh,
    float* __restrict__ xzp) {
  __shared__ unsigned short As[128 * 64];
  __shared__ unsigned short Bs[128 * 64];
  const int tid  = threadIdx.x;
  const int lane = tid & 63;
  const int wid  = tid >> 6;
  const int wm   = (wid >> 1) * 64;
  const int wn   = (wid & 1) * 64;
  const int l15  = lane & 15;
  const int l4   = lane >> 4;
  const long bm  = blockIdx.x;
  const long bn  = blockIdx.y;

  f32x4 acc[4][4];
#pragma unroll
  for (int mt = 0; mt < 4; ++mt)
#pragma unroll
    for (int nt = 0; nt < 4; ++nt) acc[mt][nt] = f32x4{0.f, 0.f, 0.f, 0.f};

  const float* Ab = A + bm * 128 * 512;
  const float* Wb = W + bn * 128 * 512;
  const int r0 = tid >> 4;
  const int cq = (tid & 15) * 4;

  for (int k0 = 0; k0 < 512; k0 += 64) {
#pragma unroll
    for (int pass = 0; pass < 8; ++pass) {
      const int r = pass * 16 + r0;
      const float4v va = *(const float4v*)(Ab + (long)r * 512 + k0 + cq);
      const float4v vb = *(const float4v*)(Wb + (long)r * 512 + k0 + cq);
      u16x4 pa, pb;
#pragma unroll
      for (int j = 0; j < 4; ++j) { pa[j] = f2bf(va[j]); pb[j] = f2bf(vb[j]); }
      const int boff = r * 128 + ((cq * 2) ^ ((r & 7) << 4));
      *(u16x4*)((char*)As + boff) = pa;
      *(u16x4*)((char*)Bs + boff) = pb;
    }
    __syncthreads();
#pragma unroll
    for (int kk = 0; kk < 2; ++kk) {
      short8 af[4], bfv[4];
#pragma unroll
      for (int mt = 0; mt < 4; ++mt) {
        const int row = wm + mt * 16 + l15;
        af[mt] = *(const short8*)((const char*)As + row * 128 +
                                  ((kk * 64 + l4 * 16) ^ ((row & 7) << 4)));
      }
#pragma unroll
      for (int nt = 0; nt < 4; ++nt) {
        const int row = wn + nt * 16 + l15;
        bfv[nt] = *(const short8*)((const char*)Bs + row * 128 +
                                   ((kk * 64 + l4 * 16) ^ ((row & 7) << 4)));
      }
#pragma unroll
      for (int mt = 0; mt < 4; ++mt)
#pragma unroll
        for (int nt = 0; nt < 4; ++nt)
          acc[mt][nt] = __builtin_amdgcn_mfma_f32_16x16x32_bf16(af[mt], bfv[nt], acc[mt][nt], 0, 0, 0);
    }
    __syncthreads();
  }

#pragma unroll
  for (int nt = 0; nt < 4; ++nt) {
    const int gn = (int)(bn * 128) + wn + nt * 16 + l15;
    const float bias = bih[gn] + bhh[gn];
    const int g2  = gn >> 9;          // gate
    const int hh  = gn & 511;
    const int nb2 = hh >> 4;
    const int en2 = hh & 15;
#pragma unroll
    for (int mt = 0; mt < 4; ++mt) {
      const int m0 = (int)(bm * 128) + wm + mt * 16 + l4 * 4;
#pragma unroll
      for (int r = 0; r < 4; ++r) {
        const int m = m0 + r;
        const int tt2 = m >> 6, brow = m & 63;
        const int mb2 = brow >> 4, em2 = brow & 15;
        xzp[((((size_t)tt2 * 4 + mb2) * 32 + nb2) << 10) + em2 * 64 + g2 * 16 + en2] =
            acc[mt][nt][r] + bias;
      }
    }
  }
}

// ------------------------------------------------------- recurrent core
// Grid 128 = 4 batch-tiles (mb) x 32 hid-tiles (nb). Flagless: exchange words
// are self-validating (tag | bf16). Consumers issue next-step loads during the
// current step's tail (optimistic), validate per-32B granule at entry, and
// selectively reload stale granules. Counted vmcnt(1) keeps the deferred ys
// store's ack OFF the critical path (FIFO: it is the only op newer than the
// data loads).
__global__ __launch_bounds__(256, 1) void lstm_steps(
    const float* __restrict__ xzp,     // [Tc*4*32][1024]
    const float* __restrict__ Whh,     // [2048][512]
    const float* __restrict__ alpha_p,
    float* __restrict__ out,           // d_out
    unsigned int* __restrict__ hb2,    // 2 x [64][512] tagged u32
    float* __restrict__ cst, float* __restrict__ hst,
    int t0, int Tc) {
  const int bx  = blockIdx.x;
  const int mb  = bx >> 5;
  const int nb  = bx & 31;
  const int rb0 = mb * 16;
  const int hs0 = nb * 16;
  const int tid = threadIdx.x;
  const int lane = tid & 63;
  const int w   = tid >> 6;        // wave = gate index
  const int l15 = lane & 15;
  const int l4  = lane >> 4;

  // h rows as 16B chunks: addr = c*256 + ((r ^ (c&15))<<4)   (R4-proven floor)
  __shared__ __align__(16) unsigned short h_lds[16 * HID];   // 16 KB
  __shared__ __align__(16) float gates[4][16][20];

  // W_hh fragments: gate w, hid cols hs0..hs0+15, full K=512 (64 VGPRs).
  short8 wf[16];
  {
    const float* wr = Whh + (long)(w * HID + hs0 + l15) * HID + l4 * 8;
#pragma unroll
    for (int ks = 0; ks < 16; ++ks) {
      const float4v lo = *(const float4v*)(wr + ks * 32);
      const float4v hi = *(const float4v*)(wr + ks * 32 + 4);
      short8 f;
#pragma unroll
      for (int j = 0; j < 4; ++j) {
        f[j]     = (short)f2bf(lo[j]);
        f[j + 4] = (short)f2bf(hi[j]);
      }
      wf[ks] = f;
    }
  }
  const float a = alpha_p[0];
  const float oma = 1.0f - a;

  const int em = tid >> 4;          // elementwise row 0..15
  const int en = tid & 15;          // elementwise col 0..15
  float cp = cst[(long)(rb0 + em) * HID + hs0 + en];
  float hp = hst[(long)(rb0 + em) * HID + hs0 + en];

  const long YS = (long)T_TOT * BATCH * HID;

  // -------- prologue: issue X(t0) then D(t0) (order matters for vmcnt FIFO)
  float xz0, xz1, xz2, xz3;
  u32x4 sa[4], sb[4];
  {
    const float* xb = xzp + (((size_t)0 * 4 + mb) * 32 + nb) * 1024 + w * 16 + l15;
    asm volatile("global_load_dword %0, %1, off" : "=v"(xz0) : "v"(xb + (l4 * 4 + 0) * 64));
    asm volatile("global_load_dword %0, %1, off" : "=v"(xz1) : "v"(xb + (l4 * 4 + 1) * 64));
    asm volatile("global_load_dword %0, %1, off" : "=v"(xz2) : "v"(xb + (l4 * 4 + 2) * 64));
    asm volatile("global_load_dword %0, %1, off" : "=v"(xz3) : "v"(xb + (l4 * 4 + 3) * 64));
    const unsigned int* p0 = hb2 + (size_t)(t0 & 1) * BH + (size_t)(rb0 + w) * HID + lane * 8;
#pragma unroll
    for (int i = 0; i < 4; ++i) {
      const unsigned int* p = p0 + (size_t)i * 4 * HID;
      asm volatile("global_load_dwordx4 %0, %1, off sc0 sc1" : "=v"(sa[i]) : "v"(p));
      asm volatile("global_load_dwordx4 %0, %1, off sc0 sc1" : "=v"(sb[i]) : "v"(p + 4));
    }
  }

  for (int tt = 0; tt < Tc; ++tt) {
    const int t = t0 + tt;

    // Entry wait. Steady state FIFO: [exch(1), X(4), D(8), ys(1)] ->
    // vmcnt(1) completes exch+X+D, leaves the ys store ack in flight.
    if (tt == 0) asm volatile("s_waitcnt vmcnt(0)" ::: "memory");
    else         asm volatile("s_waitcnt vmcnt(1)" ::: "memory");
    __builtin_amdgcn_sched_barrier(0);

    // Per-granule tag validation; selective reload of stale granules.
    {
      const unsigned wantHi = ((unsigned)t) << 16;
      const unsigned int* p0 = hb2 + (size_t)(t & 1) * BH +
                               (size_t)(rb0 + w) * HID + lane * 8;
      for (;;) {
        unsigned bad = 0u;
#pragma unroll
        for (int i = 0; i < 4; ++i) {
          unsigned d = 0u;
#pragma unroll
          for (int j = 0; j < 4; ++j)
            d |= ((sa[i][j] ^ wantHi) | (sb[i][j] ^ wantHi));
          if (d & 0xFFFF0000u) bad |= (1u << i);
        }
        if (!__any(bad != 0u)) break;
#pragma unroll
        for (int i = 0; i < 4; ++i)
          if (bad & (1u << i)) {
            const unsigned int* p = p0 + (size_t)i * 4 * HID;
            asm volatile("global_load_dwordx4 %0, %1, off sc0 sc1" : "=v"(sa[i]) : "v"(p));
            asm volatile("global_load_dwordx4 %0, %1, off sc0 sc1" : "=v"(sb[i]) : "v"(p + 4));
          }
        asm volatile("s_waitcnt vmcnt(0)" ::: "memory");
        __builtin_amdgcn_sched_barrier(0);
      }
    }

    // Pack lo16s -> one 16B chunk per (row, c=lane); R4-proven write pattern.
#pragma unroll
    for (int i = 0; i < 4; ++i) {
      u32x4 pk;
      pk[0] = __builtin_amdgcn_perm(sa[i][1], sa[i][0], 0x05040100u);
      pk[1] = __builtin_amdgcn_perm(sa[i][3], sa[i][2], 0x05040100u);
      pk[2] = __builtin_amdgcn_perm(sb[i][1], sb[i][0], 0x05040100u);
      pk[3] = __builtin_amdgcn_perm(sb[i][3], sb[i][2], 0x05040100u);
      const int r = 4 * i + w;
      const int c = lane;
      *(u32x4*)((char*)h_lds + c * 256 + ((r ^ (c & 15)) << 4)) = pk;
    }
    bar_lds();

    // [16 x 16] = h[16 x 512] @ W^T, 4 interleaved accumulator chains.
    f32x4 acc[4];
    acc[0][0] = xz0; acc[0][1] = xz1; acc[0][2] = xz2; acc[0][3] = xz3;
    acc[1] = f32x4{0.f, 0.f, 0.f, 0.f};
    acc[2] = acc[1];
    acc[3] = acc[1];
#pragma unroll
    for (int ks = 0; ks < 16; ++ks) {
      const int c = ks * 4 + l4;
      const short8 af = *(const short8*)((const char*)h_lds + c * 256 +
                                         ((l15 ^ (c & 15)) << 4));
      acc[ks & 3] = __builtin_amdgcn_mfma_f32_16x16x32_bf16(af, wf[ks], acc[ks & 3], 0, 0, 0);
    }
    {
      const f32x4 s = (acc[0] + acc[1]) + (acc[2] + acc[3]);
#pragma unroll
      for (int r = 0; r < 4; ++r)
        gates[w][l4 * 4 + r][l15] = s[r];
    }
    bar_lds();

    // Elementwise: one element per thread; c/h state lives in registers.
    const float gi = gates[0][em][en], gf = gates[1][em][en];
    const float gg = gates[2][em][en], go = gates[3][em][en];
    const float ii = sigm(gi), ff = sigm(gf), oo = sigm(go);
    const float g  = tanh_fast(gg);
    const float cn = ff * cp + ii * g;
    const float hn = oo * tanh_fast(cn);
    const float co = a * cn + oma * cp;
    const float ho = a * hn + oma * hp;
    cp = co;
    hp = ho;

    // (3) Self-validating exchange store: tag(t+1) | bf16(h'). No drain.
    {
      unsigned int* dst = hb2 + (size_t)((t + 1) & 1) * BH +
                          (long)(rb0 + em) * HID + hs0 + en;
      const unsigned w32 = (((unsigned)(t + 1)) << 16) | (unsigned)f2bf(ho);
      asm volatile("global_store_dword %0, %1, off sc0 sc1"
                   :: "v"((const void*)dst), "v"(w32) : "memory");
    }

    if (tt < Tc - 1) {
      // (4) X loads for tt+1.
      const float* xb = xzp + (((size_t)(tt + 1) * 4 + mb) * 32 + nb) * 1024 +
                        w * 16 + l15;
      asm volatile("global_load_dword %0, %1, off" : "=v"(xz0) : "v"(xb + (l4 * 4 + 0) * 64));
      asm volatile("global_load_dword %0, %1, off" : "=v"(xz1) : "v"(xb + (l4 * 4 + 1) * 64));
      asm volatile("global_load_dword %0, %1, off" : "=v"(xz2) : "v"(xb + (l4 * 4 + 2) * 64));
      asm volatile("global_load_dword %0, %1, off" : "=v"(xz3) : "v"(xb + (l4 * 4 + 3) * 64));
      // (5) D loads for t+1 (optimistic; tags re-validate at next entry).
      const unsigned int* pn = hb2 + (size_t)((t + 1) & 1) * BH +
                               (size_t)(rb0 + w) * HID + lane * 8;
#pragma unroll
      for (int i = 0; i < 4; ++i) {
        const unsigned int* p = pn + (size_t)i * 4 * HID;
        asm volatile("global_load_dwordx4 %0, %1, off sc0 sc1" : "=v"(sa[i]) : "v"(p));
        asm volatile("global_load_dwordx4 %0, %1, off sc0 sc1" : "=v"(sb[i]) : "v"(p + 4));
      }
      // (6) Deferred ys store of step t (behind the data loads in FIFO).
      const float* op = out + ((long)t * BATCH + rb0 + em) * HID + hs0 + en;
      asm volatile("global_store_dword %0, %1, off"
                   :: "v"((const void*)op), "v"(ho) : "memory");
    }
  }

  // -------- epilogue: last step's outputs + persisted state.
  {
    const int tl = t0 + Tc - 1;
    out[((long)tl * BATCH + rb0 + em) * HID + hs0 + en] = hp;
    if (t0 + Tc == T_TOT) {
      out[YS + (long)(rb0 + em) * HID + hs0 + en] = hp;
      out[YS + BATCH * HID + (long)(rb0 + em) * HID + hs0 + en] = cp;
    }
    cst[(long)(rb0 + em) * HID + hs0 + en] = cp;
    hst[(long)(rb0 + em) * HID + hs0 + en] = hp;
  }
}

// ---------------------------------------------------------------- host
extern "C" void kernel_launch(void* const* d_in, const int* in_sizes, int n_in,
                              void* d_out, int out_size, void* d_ws, size_t ws_size,
                              hipStream_t stream) {
  const float* x     = (const float*)d_in[0];
  const float* h0    = (const float*)d_in[1];
  const float* c0    = (const float*)d_in[2];
  const float* W_ih  = (const float*)d_in[3];
  const float* W_hh  = (const float*)d_in[4];
  const float* b_ih  = (const float*)d_in[5];
  const float* b_hh  = (const float*)d_in[6];
  const float* alpha = (const float*)d_in[7];
  float* out = (float*)d_out;

  char* ws = (char*)d_ws;
  unsigned int* hb2 = (unsigned int*)(ws + 0);              // 256 KB tagged h
  float* cst = (float*)(ws + 262144);                       // 128 KB
  float* hst = (float*)(ws + 393216);                       // 128 KB
  float* xzp = (float*)(ws + 524288);                       // Tc*512 KB

  int Tc = T_TOT;
  while ((size_t)Tc * 524288ull + 524288ull > ws_size && Tc > 2) Tc >>= 1;

  init_k<<<128, 256, 0, stream>>>(h0, c0, hb2, cst, hst);
  for (int t0 = 0; t0 < T_TOT; t0 += Tc) {
    dim3 gg(Tc / 2, 16);
    xz_gemm<<<gg, 256, 0, stream>>>(x + (size_t)t0 * BATCH * 512,
                                    W_ih, b_ih, b_hh, xzp);
    lstm_steps<<<NGRID, 256, 0, stream>>>(xzp, W_hh, alpha, out, hb2,
                                          cst, hst, t0, Tc);
  }
}